// Round 17
// baseline (239.183 us; speedup 1.0000x reference)
//
#include <hip/hip_runtime.h>

// HeaNet R17 = R16 (211.7us; edge 68.2) + in-block layer loop with G held in
// its OWN LDS region (R7's failure was lifted register arrays, not the loop:
// here cross-layer state = gbuf(LDS) + loop counter + 4 bias scalars only).
//  - G-stage (16 exp2 + cvt + stores) and ce/zs staging run ONCE per block
//    instead of 6x; barriers 18 -> 13 per group; dummies exit once.
//  - LDS: gbuf 9.2KB + tbuf 17.4KB + ce/zs = 27.1KB (not occupancy-limiting
//    at 4 blocks/CU). All per-layer math identical to R16.

#define NNODES 8192
#define NGRAPH 32
#define NELEM  5
#define NEDGE  131072
#define HD     128
#define FD     128
#define GD     50
#define LL     6
#define NC     160
#define NZ     100
#define CUT    10.0f
#define LOG2_  0.69314718055994531f
#define LOG2E_ 1.44269504088896340f
#define QDC    0.84932181f        // sqrt(0.5*log2e)

#define CAP    1024               // per-cid slot capacity
#define PADE   (NC * CAP)         // 163840
#define PADG   (PADE / 64)        // 2560 groups
#define GPITCH 72                 // halfs per G row
#define TPITCH 136                // halfs per T row
#define CSTR   16                 // cursor stride in ints (64B cacheline)

#define W1F_ELEMS (LL * 2 * 8 * 64 * 8)   // 49152
#define W2F_ELEMS (LL * 4 * 8 * 64 * 8)   // 98304
#define NSCATB   (NEDGE / 256)                     // 512
#define NFRAGB   ((W1F_ELEMS + W2F_ELEMS) / 256)   // 576
#define NXHZB    (LL * NZ / 2)                     // 300
#define NB2PB    3                                 // 6*128 = 768 = 3*256

typedef _Float16 half8 __attribute__((ext_vector_type(8)));
typedef float floatx4 __attribute__((ext_vector_type(4)));

#if __has_builtin(__builtin_amdgcn_exp2f)
#define EXP2F(x) __builtin_amdgcn_exp2f(x)
#else
#define EXP2F(x) __expf((x) * LOG2_)
#endif
#if __has_builtin(__builtin_amdgcn_logf)
#define LOG2F_(x) __builtin_amdgcn_logf(x)
#else
#define LOG2F_(x) (__logf(x) * LOG2E_)
#endif

__device__ __forceinline__ float ssp(float x) {         // stable form (small kernels)
    float m = fmaxf(x, 0.0f);
    float z = __expf(-fabsf(x));
    return m + __logf(1.0f + z) - LOG2_;
}

// ---------- K1: scatter + counts + B-fragments + xh_z + b2p (independent) ----------
__global__ __launch_bounds__(256) void setup_kernel(
    const float* __restrict__ pos, const int* __restrict__ ei,
    const int* __restrict__ comp_id, const int* __restrict__ z,
    const float* __restrict__ w1, const float* __restrict__ w2,
    const float* __restrict__ b2in,
    const float* __restrict__ emb, const float* __restrict__ cf1,
    int* __restrict__ counts, int* __restrict__ cursor,
    float* __restrict__ ew_s, float* __restrict__ c_s, int* __restrict__ zsrc_s,
    _Float16* __restrict__ w1f, _Float16* __restrict__ w2f,
    float* __restrict__ xh_z, float* __restrict__ b2p)
{
    int bx = blockIdx.x;
    int tid = threadIdx.x;
    if (bx < NSCATB) {
        int e = bx * 256 + tid;
        int s = ei[e], d = ei[NEDGE + e];
        float dx = pos[3*s]   - pos[3*d];
        float dy = pos[3*s+1] - pos[3*d+1];
        float dz = pos[3*s+2] - pos[3*d+2];
        float d2 = dx*dx + dy*dy + dz*dz;
        float ew = sqrtf(d2);
        float C  = CUT / (1e-10f + d2) - 1.0f;
        int cid = comp_id[d];
        int idx = cid * CAP + atomicAdd(&cursor[cid * CSTR], 1);
        ew_s[idx] = ew; c_s[idx] = C; zsrc_s[idx] = z[s];
        if (e < NNODES) atomicAdd(&counts[comp_id[e]], 1);
        return;
    }
    int fx = bx - NSCATB;
    if (fx < NFRAGB) {
        int idx = fx * 256 + tid;
        if (idx < W1F_ELEMS) {
            int j = idx & 7, lane = (idx >> 3) & 63, tcg = (idx >> 9) & 7;
            int kb = (idx >> 12) & 1, l = idx >> 13;
            int k = kb * 32 + (lane >> 4) * 8 + j;
            int col = tcg * 16 + (lane & 15);
            float v = (k < GD) ? w1[(l * GD + k) * FD + col] : 0.0f;
            w1f[idx] = (_Float16)(v * LOG2E_);               // pre-scaled by log2e
        } else {
            int id2 = idx - W1F_ELEMS;
            int j = id2 & 7, lane = (id2 >> 3) & 63, tcg = (id2 >> 9) & 7;
            int kb = (id2 >> 12) & 3, l = id2 >> 14;
            int k = kb * 32 + (lane >> 4) * 8 + j;
            int col = tcg * 16 + (lane & 15);
            w2f[id2] = (_Float16)(LOG2_ * w2[(l * FD + k) * FD + col]);   // ln2-folded
        }
        return;
    }
    int bz = fx - NFRAGB;
    if (bz < NXHZB) {
        int l = bz / (NZ / 2);
        int zv = (bz % (NZ / 2)) * 2 + (tid >> 7);
        int f = tid & 127;
        const float* h = emb + zv * HD;
        const float* w = cf1 + l * HD * FD;
        float acc = 0.0f;
        #pragma unroll 8
        for (int k = 0; k < HD; ++k) acc = fmaf(h[k], w[k * FD + f], acc);
        xh_z[(l * NZ + zv) * FD + f] = acc;
    } else {
        // b2p[l][fo] = b2[l][fo] - sum_fi f32(f16(ln2*w2[l][fi][fo]))
        int idx2 = (bz - NXHZB) * 256 + tid;    // 0..767
        int l = idx2 >> 7, fo = idx2 & 127;
        float sum = 0.0f;
        #pragma unroll 8
        for (int fi = 0; fi < FD; ++fi)
            sum += (float)(_Float16)(LOG2_ * w2[(l * FD + fi) * FD + fo]);
        b2p[idx2] = b2in[l * FD + fo] - sum;
    }
}

// ---------- K2 (hot): 64 edges x 128 features x ALL 6 LAYERS per block ----------
// grid = PADG, g-major: cid = bx % NC, g = bx / NC -> dummies cluster at tail.
// Cross-layer state: gbuf (LDS) + 4 bias scalars per layer. No lifted arrays.
__global__ __launch_bounds__(256, 4) void edge_kernel(
    const float* __restrict__ ew_s, const float* __restrict__ c_s,
    const int* __restrict__ zsrc_s,
    const _Float16* __restrict__ w1f, const float* __restrict__ b1_,
    const _Float16* __restrict__ w2f, const float* __restrict__ b2p_,
    const float* __restrict__ xh_z, float* __restrict__ comp_acc)
{
    __shared__ __align__(16) _Float16 gbuf[64 * GPITCH];   // layer-invariant G
    __shared__ __align__(16) _Float16 tbuf[64 * TPITCH];   // per-layer S
    __shared__ float ce_l[64];
    __shared__ int   zs_l[64];                              // byte offsets

    const int tid  = threadIdx.x;
    const int lane = tid & 63;
    const int l15  = lane & 15;
    const int quad = lane >> 4;
    const int fq   = __builtin_amdgcn_readfirstlane(tid >> 6);
    const int cid  = blockIdx.x % NC;
    const int gg   = blockIdx.x / NC;
    const int g0   = cid * CAP + gg * 64;

    const float delta = CUT / (GD - 1);
    const float Qe = QDC / delta;                 // u = Qe*ew - k*QDC

    const float ce = c_s[g0 + lane];
    if (__all(ce == 0.0f)) return;                 // dummy group: skips all 6 layers
    if (tid < 64) {
        ce_l[tid] = ce;
        zs_l[tid] = zsrc_s[g0 + tid] * (FD * 4);   // pre-scaled byte offset
    }
    const int colbase = fq * 32 + l15;

    // ---- stage G once: exp2(-u^2), 16/thread ----
    {
        const float qewr = ew_s[g0 + lane] * Qe;
        half8 ga, gb;
        #pragma unroll
        for (int i = 0; i < 8; ++i) {
            float u0 = qewr - (fq * 16 + i) * QDC;
            float u1 = qewr - (fq * 16 + 8 + i) * QDC;
            ga[i] = (_Float16)EXP2F(-(u0 * u0));
            gb[i] = (_Float16)EXP2F(-(u1 * u1));
        }
        *(half8*)&gbuf[lane * GPITCH + fq * 16]     = ga;
        *(half8*)&gbuf[lane * GPITCH + fq * 16 + 8] = gb;
    }
    __syncthreads();

    const half8* w1fp = (const half8*)w1f;
    const half8* w2fp = (const half8*)w2f;

    #pragma unroll 1
    for (int l = 0; l < LL; ++l) {
        const float b1c0 = b1_[l * FD + colbase] * LOG2E_;
        const float b1c1 = b1_[l * FD + colbase + 16] * LOG2E_;
        const float b2c0 = b2p_[l * FD + colbase];
        const float b2c1 = b2p_[l * FD + colbase + 16];

        // ---- GEMM-1: T' = G @ (W1*log2e) (+b1*log2e via C-init) ----
        floatx4 accT[4][2];
        #pragma unroll
        for (int tr = 0; tr < 4; ++tr) {
            accT[tr][0] = (floatx4){b1c0, b1c0, b1c0, b1c0};
            accT[tr][1] = (floatx4){b1c1, b1c1, b1c1, b1c1};
        }
        #pragma unroll
        for (int kb = 0; kb < 2; ++kb) {
            half8 bf0 = w1fp[((l * 2 + kb) * 8 + fq * 2 + 0) * 64 + lane];
            half8 bf1 = w1fp[((l * 2 + kb) * 8 + fq * 2 + 1) * 64 + lane];
            #pragma unroll
            for (int tr = 0; tr < 4; ++tr) {
                half8 af = *(const half8*)&gbuf[(tr * 16 + l15) * GPITCH + kb * 32 + quad * 8];
                accT[tr][0] = __builtin_amdgcn_mfma_f32_16x16x32_f16(af, bf0, accT[tr][0], 0, 0, 0);
                accT[tr][1] = __builtin_amdgcn_mfma_f32_16x16x32_f16(af, bf1, accT[tr][1], 0, 0, 0);
            }
        }
        __syncthreads();       // WAR: previous layer's tbuf reads complete

        // ---- S = log2(1 + 2^t'); store raw (ln2/-1 folded into w2f/b2p) ----
        #pragma unroll
        for (int tr = 0; tr < 4; ++tr) {
            #pragma unroll
            for (int tcl = 0; tcl < 2; ++tcl) {
                #pragma unroll
                for (int r = 0; r < 4; ++r) {
                    float ee = EXP2F(accT[tr][tcl][r]);
                    tbuf[(tr * 16 + quad * 4 + r) * TPITCH + fq * 32 + tcl * 16 + l15]
                        = (_Float16)LOG2F_(1.0f + ee);
                }
            }
        }
        __syncthreads();

        // ---- GEMM-2: Wm = S @ (ln2*W2) (+b2p via C-init) ----
        floatx4 accW[4][2];
        #pragma unroll
        for (int tr = 0; tr < 4; ++tr) {
            accW[tr][0] = (floatx4){b2c0, b2c0, b2c0, b2c0};
            accW[tr][1] = (floatx4){b2c1, b2c1, b2c1, b2c1};
        }
        #pragma unroll
        for (int kb = 0; kb < 4; ++kb) {
            half8 bf0 = w2fp[((l * 4 + kb) * 8 + fq * 2 + 0) * 64 + lane];
            half8 bf1 = w2fp[((l * 4 + kb) * 8 + fq * 2 + 1) * 64 + lane];
            #pragma unroll
            for (int tr = 0; tr < 4; ++tr) {
                half8 af = *(const half8*)&tbuf[(tr * 16 + l15) * TPITCH + kb * 32 + quad * 8];
                accW[tr][0] = __builtin_amdgcn_mfma_f32_16x16x32_f16(af, bf0, accW[tr][0], 0, 0, 0);
                accW[tr][1] = __builtin_amdgcn_mfma_f32_16x16x32_f16(af, bf1, accW[tr][1], 0, 0, 0);
            }
        }

        // ---- epilogue: p = ce*xh; fmaf reduce; cross-quad butterfly ----
        const char* xb = (const char*)(xh_z + l * NZ * FD) + colbase * 4;
        float s0 = 0.0f, s1 = 0.0f;
        #pragma unroll
        for (int tr = 0; tr < 4; ++tr) {
            #pragma unroll
            for (int r = 0; r < 4; ++r) {
                const int e = tr * 16 + quad * 4 + r;
                const float cee = ce_l[e];
                const float* xr = (const float*)(xb + zs_l[e]);
                float p0 = cee * xr[0];
                float p1 = cee * xr[16];
                s0 = fmaf(accW[tr][0][r], p0, s0);
                s1 = fmaf(accW[tr][1][r], p1, s1);
            }
        }
        s0 += __shfl_xor(s0, 16); s0 += __shfl_xor(s0, 32);
        s1 += __shfl_xor(s1, 16); s1 += __shfl_xor(s1, 32);
        float* cacc = comp_acc + (l * NC + cid) * FD + fq * 32;
        if (quad == 0) {
            atomicAdd(&cacc[l15],      s0);
            atomicAdd(&cacc[l15 + 16], s1);
        }
    }
}

// ---------- K3: per-component update ((NC,LL) = 960 blocks) ----------
__global__ __launch_bounds__(128) void comp_kernel(
    const float* __restrict__ comp_acc, const int* __restrict__ counts,
    const float* __restrict__ cf2w, const float* __restrict__ cf2b,
    const float* __restrict__ intw, const float* __restrict__ intb,
    float* __restrict__ types_acc)
{
    int c = blockIdx.x, l = blockIdx.y, f = threadIdx.x;
    __shared__ float comp[FD];
    __shared__ float sx[FD];
    comp[f] = comp_acc[(l * NC + c) * FD + f] / (float)counts[c];
    __syncthreads();
    float acc = cf2b[l * HD + f];
    const float* w = cf2w + l * FD * HD;
    #pragma unroll 8
    for (int k = 0; k < FD; ++k) acc = fmaf(comp[k], w[k * HD + f], acc);
    sx[f] = ssp(acc);
    __syncthreads();
    float acc2 = intb[l * HD + f];
    const float* wi = intw + l * HD * HD;
    #pragma unroll 8
    for (int k = 0; k < HD; ++k) acc2 = fmaf(sx[k], wi[k * HD + f], acc2);
    atomicAdd(&types_acc[c * HD + f], acc2);
}

// ---------- K4: readout ----------
__global__ __launch_bounds__(64) void readout_kernel(
    const float* __restrict__ types_acc, const float* __restrict__ emb,
    const int* __restrict__ comps_z,
    const float* __restrict__ w1, const float* __restrict__ b1,
    const float* __restrict__ w2, const float* __restrict__ b2,
    float* __restrict__ out)
{
    int b = blockIdx.x, lane = threadIdx.x;
    float sum = 0.0f;
    for (int cc = 0; cc < NELEM; ++cc) {
        int c = b * NELEM + cc;
        int zc = comps_z[c];
        float acc = b1[lane];
        const float* ta = types_acc + c * HD;
        const float* eb = emb + zc * HD;
        #pragma unroll 8
        for (int k = 0; k < HD; ++k) acc = fmaf(ta[k] + eb[k], w1[k * 64 + lane], acc);
        sum += ssp(acc) * w2[lane];
    }
    #pragma unroll
    for (int s = 32; s > 0; s >>= 1) sum += __shfl_xor(sum, s);
    if (lane == 0) out[b] = sum + (float)NELEM * b2[0];
}

extern "C" void kernel_launch(void* const* d_in, const int* in_sizes, int n_in,
                              void* d_out, int out_size, void* d_ws, size_t ws_size,
                              hipStream_t stream) {
    (void)in_sizes; (void)n_in; (void)out_size; (void)ws_size;
    const float* pos     = (const float*)d_in[0];
    const float* emb     = (const float*)d_in[1];
    const float* mlp_w1  = (const float*)d_in[2];
    const float* mlp_b1  = (const float*)d_in[3];
    const float* mlp_w2  = (const float*)d_in[4];
    const float* mlp_b2  = (const float*)d_in[5];
    const float* cf1     = (const float*)d_in[6];
    const float* cf2w    = (const float*)d_in[7];
    const float* cf2b    = (const float*)d_in[8];
    const float* intw    = (const float*)d_in[9];
    const float* intb    = (const float*)d_in[10];
    const float* ow1     = (const float*)d_in[11];
    const float* ob1     = (const float*)d_in[12];
    const float* ow2     = (const float*)d_in[13];
    const float* ob2     = (const float*)d_in[14];
    const int*   z       = (const int*)d_in[15];
    const int*   comp_id = (const int*)d_in[16];
    const int*   ei      = (const int*)d_in[17];
    const int*   comps_z = (const int*)d_in[18];
    float* out = (float*)d_out;

    char* ws = (char*)d_ws;
    size_t off = 0;
    auto alloc = [&](size_t bytes) -> void* {
        void* p = ws + off;
        off += (bytes + 255) & ~(size_t)255;
        return p;
    };
    // zeroed prefix: comp_acc | counts | types_acc | cursor | c_s | zsrc_s
    float* comp_acc  = (float*)alloc((size_t)LL * NC * FD * 4);
    int*   counts    = (int*)  alloc(NC * 4);
    float* types_acc = (float*)alloc((size_t)NC * HD * 4);
    int*   cursor    = (int*)  alloc(NC * CSTR * 4);
    float* c_s       = (float*)alloc((size_t)PADE * 4);
    int*   zsrc_s    = (int*)  alloc((size_t)PADE * 4);
    size_t zero_bytes = off;
    float* ew_s     = (float*)alloc((size_t)PADE * 4);
    float* xh_z     = (float*)alloc((size_t)LL * NZ * FD * 4);
    float* b2p      = (float*)alloc((size_t)LL * FD * 4);
    _Float16* w1f   = (_Float16*)alloc((size_t)W1F_ELEMS * 2);
    _Float16* w2f   = (_Float16*)alloc((size_t)W2F_ELEMS * 2);

    hipMemsetAsync(d_ws, 0, zero_bytes, stream);

    setup_kernel<<<NSCATB + NFRAGB + NXHZB + NB2PB, 256, 0, stream>>>(
        pos, ei, comp_id, z, mlp_w1, mlp_w2, mlp_b2, emb, cf1,
        counts, cursor, ew_s, c_s, zsrc_s, w1f, w2f, xh_z, b2p);
    edge_kernel <<<PADG, 256, 0, stream>>>(ew_s, c_s, zsrc_s,
                                           w1f, mlp_b1, w2f, b2p,
                                           xh_z, comp_acc);
    comp_kernel <<<dim3(NC, LL), 128, 0, stream>>>(comp_acc, counts, cf2w, cf2b,
                                                   intw, intb, types_acc);
    readout_kernel<<<NGRAPH, 64, 0, stream>>>(types_acc, emb, comps_z,
                                              ow1, ob1, ow2, ob2, out);
}

// Round 18
// 209.654 us; speedup vs baseline: 1.1408x; 1.1408x over previous
//
#include <hip/hip_runtime.h>

// HeaNet R18 = R16 reverted verbatim (R17's in-block layer loop cut occupancy
// 62->42% via 27KB LDS: third failed hoist of layer-invariant work -- closed)
// + one change: edge_kernel __launch_bounds__(256,4) -> (256,8). R16 resources
// (36 VGPR, 17.9KB LDS) permit 8 blocks/CU; declare it for latency hiding.

#define NNODES 8192
#define NGRAPH 32
#define NELEM  5
#define NEDGE  131072
#define HD     128
#define FD     128
#define GD     50
#define LL     6
#define NC     160
#define NZ     100
#define CUT    10.0f
#define LOG2_  0.69314718055994531f
#define LOG2E_ 1.44269504088896340f
#define QDC    0.84932181f        // sqrt(0.5*log2e)

#define CAP    1024               // per-cid slot capacity
#define PADE   (NC * CAP)         // 163840
#define PADG   (PADE / 64)        // 2560 groups per layer
#define GPITCH 72                 // halfs per G row
#define TPITCH 136                // halfs per T row
#define CSTR   16                 // cursor stride in ints (64B cacheline)

#define W1F_ELEMS (LL * 2 * 8 * 64 * 8)   // 49152
#define W2F_ELEMS (LL * 4 * 8 * 64 * 8)   // 98304
#define NSCATB   (NEDGE / 256)                     // 512
#define NFRAGB   ((W1F_ELEMS + W2F_ELEMS) / 256)   // 576
#define NXHZB    (LL * NZ / 2)                     // 300
#define NB2PB    3                                 // 6*128 = 768 = 3*256

typedef _Float16 half8 __attribute__((ext_vector_type(8)));
typedef float floatx4 __attribute__((ext_vector_type(4)));

#if __has_builtin(__builtin_amdgcn_exp2f)
#define EXP2F(x) __builtin_amdgcn_exp2f(x)
#else
#define EXP2F(x) __expf((x) * LOG2_)
#endif
#if __has_builtin(__builtin_amdgcn_logf)
#define LOG2F_(x) __builtin_amdgcn_logf(x)
#else
#define LOG2F_(x) (__logf(x) * LOG2E_)
#endif

__device__ __forceinline__ float ssp(float x) {         // stable form (small kernels)
    float m = fmaxf(x, 0.0f);
    float z = __expf(-fabsf(x));
    return m + __logf(1.0f + z) - LOG2_;
}

// ---------- K1: scatter + counts + B-fragments + xh_z + b2p (independent) ----------
__global__ __launch_bounds__(256) void setup_kernel(
    const float* __restrict__ pos, const int* __restrict__ ei,
    const int* __restrict__ comp_id, const int* __restrict__ z,
    const float* __restrict__ w1, const float* __restrict__ w2,
    const float* __restrict__ b2in,
    const float* __restrict__ emb, const float* __restrict__ cf1,
    int* __restrict__ counts, int* __restrict__ cursor,
    float* __restrict__ ew_s, float* __restrict__ c_s, int* __restrict__ zsrc_s,
    _Float16* __restrict__ w1f, _Float16* __restrict__ w2f,
    float* __restrict__ xh_z, float* __restrict__ b2p)
{
    int bx = blockIdx.x;
    int tid = threadIdx.x;
    if (bx < NSCATB) {
        int e = bx * 256 + tid;
        int s = ei[e], d = ei[NEDGE + e];
        float dx = pos[3*s]   - pos[3*d];
        float dy = pos[3*s+1] - pos[3*d+1];
        float dz = pos[3*s+2] - pos[3*d+2];
        float d2 = dx*dx + dy*dy + dz*dz;
        float ew = sqrtf(d2);
        float C  = CUT / (1e-10f + d2) - 1.0f;
        int cid = comp_id[d];
        int idx = cid * CAP + atomicAdd(&cursor[cid * CSTR], 1);
        ew_s[idx] = ew; c_s[idx] = C; zsrc_s[idx] = z[s];
        if (e < NNODES) atomicAdd(&counts[comp_id[e]], 1);
        return;
    }
    int fx = bx - NSCATB;
    if (fx < NFRAGB) {
        int idx = fx * 256 + tid;
        if (idx < W1F_ELEMS) {
            int j = idx & 7, lane = (idx >> 3) & 63, tcg = (idx >> 9) & 7;
            int kb = (idx >> 12) & 1, l = idx >> 13;
            int k = kb * 32 + (lane >> 4) * 8 + j;
            int col = tcg * 16 + (lane & 15);
            float v = (k < GD) ? w1[(l * GD + k) * FD + col] : 0.0f;
            w1f[idx] = (_Float16)(v * LOG2E_);               // pre-scaled by log2e
        } else {
            int id2 = idx - W1F_ELEMS;
            int j = id2 & 7, lane = (id2 >> 3) & 63, tcg = (id2 >> 9) & 7;
            int kb = (id2 >> 12) & 3, l = id2 >> 14;
            int k = kb * 32 + (lane >> 4) * 8 + j;
            int col = tcg * 16 + (lane & 15);
            w2f[id2] = (_Float16)(LOG2_ * w2[(l * FD + k) * FD + col]);   // ln2-folded
        }
        return;
    }
    int bz = fx - NFRAGB;
    if (bz < NXHZB) {
        int l = bz / (NZ / 2);
        int zv = (bz % (NZ / 2)) * 2 + (tid >> 7);
        int f = tid & 127;
        const float* h = emb + zv * HD;
        const float* w = cf1 + l * HD * FD;
        float acc = 0.0f;
        #pragma unroll 8
        for (int k = 0; k < HD; ++k) acc = fmaf(h[k], w[k * FD + f], acc);
        xh_z[(l * NZ + zv) * FD + f] = acc;
    } else {
        // b2p[l][fo] = b2[l][fo] - sum_fi f32(f16(ln2*w2[l][fi][fo]))
        int idx2 = (bz - NXHZB) * 256 + tid;    // 0..767
        int l = idx2 >> 7, fo = idx2 & 127;
        float sum = 0.0f;
        #pragma unroll 8
        for (int fi = 0; fi < FD; ++fi)
            sum += (float)(_Float16)(LOG2_ * w2[(l * FD + fi) * FD + fo]);
        b2p[idx2] = b2in[l * FD + fo] - sum;
    }
}

// ---------- K2 (hot): 64 edges x 128 features, one layer per block ----------
// grid.x = PADG, g-major: cid = bx % NC, g = bx / NC -> dummies cluster at tail.
__global__ __launch_bounds__(256, 8) void edge_kernel(
    const float* __restrict__ ew_s, const float* __restrict__ c_s,
    const int* __restrict__ zsrc_s,
    const _Float16* __restrict__ w1f, const float* __restrict__ b1_,
    const _Float16* __restrict__ w2f, const float* __restrict__ b2p_,
    const float* __restrict__ xh_z, float* __restrict__ comp_acc)
{
    __shared__ __align__(16) _Float16 smem[64 * TPITCH];   // G (64*72) then T (64*136)
    __shared__ float ce_l[64];
    __shared__ int   zs_l[64];                              // byte offsets into xh_z row space

    const int tid  = threadIdx.x;
    const int lane = tid & 63;
    const int l15  = lane & 15;
    const int quad = lane >> 4;
    const int fq   = __builtin_amdgcn_readfirstlane(tid >> 6);
    const int l    = blockIdx.y;
    const int cid  = blockIdx.x % NC;
    const int gg   = blockIdx.x / NC;
    const int g0   = cid * CAP + gg * 64;

    const float delta = CUT / (GD - 1);
    const float Qe = QDC / delta;                 // u = Qe*ew - k*QDC

    const float ce = c_s[g0 + lane];
    if (__all(ce == 0.0f)) return;                 // fully-dummy group (tail-clustered)
    if (tid < 64) {
        ce_l[tid] = ce;
        zs_l[tid] = zsrc_s[g0 + tid] * (FD * 4);   // pre-scaled byte offset
    }
    const int colbase = fq * 32 + l15;
    const float b1c0 = b1_[l * FD + colbase] * LOG2E_;
    const float b1c1 = b1_[l * FD + colbase + 16] * LOG2E_;
    const float b2c0 = b2p_[l * FD + colbase];
    const float b2c1 = b2p_[l * FD + colbase + 16];

    // ---- stage G[row][k] in LDS: exp2(-u^2), 16/thread ----
    {
        const float qewr = ew_s[g0 + lane] * Qe;
        half8 ga, gb;
        #pragma unroll
        for (int i = 0; i < 8; ++i) {
            float u0 = qewr - (fq * 16 + i) * QDC;
            float u1 = qewr - (fq * 16 + 8 + i) * QDC;
            ga[i] = (_Float16)EXP2F(-(u0 * u0));
            gb[i] = (_Float16)EXP2F(-(u1 * u1));
        }
        *(half8*)&smem[lane * GPITCH + fq * 16]     = ga;
        *(half8*)&smem[lane * GPITCH + fq * 16 + 8] = gb;
    }
    __syncthreads();

    // ---- GEMM-1: T' = G @ (W1*log2e) (+b1*log2e via C-init) ----
    floatx4 accT[4][2];
    #pragma unroll
    for (int tr = 0; tr < 4; ++tr) {
        accT[tr][0] = (floatx4){b1c0, b1c0, b1c0, b1c0};
        accT[tr][1] = (floatx4){b1c1, b1c1, b1c1, b1c1};
    }
    const half8* w1fp = (const half8*)w1f;
    #pragma unroll
    for (int kb = 0; kb < 2; ++kb) {
        half8 bf0 = w1fp[((l * 2 + kb) * 8 + fq * 2 + 0) * 64 + lane];
        half8 bf1 = w1fp[((l * 2 + kb) * 8 + fq * 2 + 1) * 64 + lane];
        #pragma unroll
        for (int tr = 0; tr < 4; ++tr) {
            half8 af = *(const half8*)&smem[(tr * 16 + l15) * GPITCH + kb * 32 + quad * 8];
            accT[tr][0] = __builtin_amdgcn_mfma_f32_16x16x32_f16(af, bf0, accT[tr][0], 0, 0, 0);
            accT[tr][1] = __builtin_amdgcn_mfma_f32_16x16x32_f16(af, bf1, accT[tr][1], 0, 0, 0);
        }
    }
    __syncthreads();                                // all G reads done before T overwrites

    // ---- S = log2(1 + 2^t'); store raw (ln2/-1 folded into w2f/b2p) ----
    #pragma unroll
    for (int tr = 0; tr < 4; ++tr) {
        #pragma unroll
        for (int tcl = 0; tcl < 2; ++tcl) {
            #pragma unroll
            for (int r = 0; r < 4; ++r) {
                float ee = EXP2F(accT[tr][tcl][r]);
                smem[(tr * 16 + quad * 4 + r) * TPITCH + fq * 32 + tcl * 16 + l15]
                    = (_Float16)LOG2F_(1.0f + ee);
            }
        }
    }
    __syncthreads();

    // ---- GEMM-2: Wm = S @ (ln2*W2) (+b2p via C-init) ----
    floatx4 accW[4][2];
    #pragma unroll
    for (int tr = 0; tr < 4; ++tr) {
        accW[tr][0] = (floatx4){b2c0, b2c0, b2c0, b2c0};
        accW[tr][1] = (floatx4){b2c1, b2c1, b2c1, b2c1};
    }
    const half8* w2fp = (const half8*)w2f;
    #pragma unroll
    for (int kb = 0; kb < 4; ++kb) {
        half8 bf0 = w2fp[((l * 4 + kb) * 8 + fq * 2 + 0) * 64 + lane];
        half8 bf1 = w2fp[((l * 4 + kb) * 8 + fq * 2 + 1) * 64 + lane];
        #pragma unroll
        for (int tr = 0; tr < 4; ++tr) {
            half8 af = *(const half8*)&smem[(tr * 16 + l15) * TPITCH + kb * 32 + quad * 8];
            accW[tr][0] = __builtin_amdgcn_mfma_f32_16x16x32_f16(af, bf0, accW[tr][0], 0, 0, 0);
            accW[tr][1] = __builtin_amdgcn_mfma_f32_16x16x32_f16(af, bf1, accW[tr][1], 0, 0, 0);
        }
    }

    // ---- epilogue: p = ce*xh once; fmaf reduce; cross-quad butterfly ----
    const char* xb = (const char*)(xh_z + l * NZ * FD) + colbase * 4;
    float s0 = 0.0f, s1 = 0.0f;
    #pragma unroll
    for (int tr = 0; tr < 4; ++tr) {
        #pragma unroll
        for (int r = 0; r < 4; ++r) {
            const int e = tr * 16 + quad * 4 + r;
            const float cee = ce_l[e];
            const float* xr = (const float*)(xb + zs_l[e]);
            float p0 = cee * xr[0];
            float p1 = cee * xr[16];
            s0 = fmaf(accW[tr][0][r], p0, s0);
            s1 = fmaf(accW[tr][1][r], p1, s1);
        }
    }
    s0 += __shfl_xor(s0, 16); s0 += __shfl_xor(s0, 32);
    s1 += __shfl_xor(s1, 16); s1 += __shfl_xor(s1, 32);
    float* cacc = comp_acc + (l * NC + cid) * FD + fq * 32;
    if (quad == 0) {
        atomicAdd(&cacc[l15],      s0);
        atomicAdd(&cacc[l15 + 16], s1);
    }
}

// ---------- K3: per-component update ((NC,LL) = 960 blocks) ----------
__global__ __launch_bounds__(128) void comp_kernel(
    const float* __restrict__ comp_acc, const int* __restrict__ counts,
    const float* __restrict__ cf2w, const float* __restrict__ cf2b,
    const float* __restrict__ intw, const float* __restrict__ intb,
    float* __restrict__ types_acc)
{
    int c = blockIdx.x, l = blockIdx.y, f = threadIdx.x;
    __shared__ float comp[FD];
    __shared__ float sx[FD];
    comp[f] = comp_acc[(l * NC + c) * FD + f] / (float)counts[c];
    __syncthreads();
    float acc = cf2b[l * HD + f];
    const float* w = cf2w + l * FD * HD;
    #pragma unroll 8
    for (int k = 0; k < FD; ++k) acc = fmaf(comp[k], w[k * HD + f], acc);
    sx[f] = ssp(acc);
    __syncthreads();
    float acc2 = intb[l * HD + f];
    const float* wi = intw + l * HD * HD;
    #pragma unroll 8
    for (int k = 0; k < HD; ++k) acc2 = fmaf(sx[k], wi[k * HD + f], acc2);
    atomicAdd(&types_acc[c * HD + f], acc2);
}

// ---------- K4: readout ----------
__global__ __launch_bounds__(64) void readout_kernel(
    const float* __restrict__ types_acc, const float* __restrict__ emb,
    const int* __restrict__ comps_z,
    const float* __restrict__ w1, const float* __restrict__ b1,
    const float* __restrict__ w2, const float* __restrict__ b2,
    float* __restrict__ out)
{
    int b = blockIdx.x, lane = threadIdx.x;
    float sum = 0.0f;
    for (int cc = 0; cc < NELEM; ++cc) {
        int c = b * NELEM + cc;
        int zc = comps_z[c];
        float acc = b1[lane];
        const float* ta = types_acc + c * HD;
        const float* eb = emb + zc * HD;
        #pragma unroll 8
        for (int k = 0; k < HD; ++k) acc = fmaf(ta[k] + eb[k], w1[k * 64 + lane], acc);
        sum += ssp(acc) * w2[lane];
    }
    #pragma unroll
    for (int s = 32; s > 0; s >>= 1) sum += __shfl_xor(sum, s);
    if (lane == 0) out[b] = sum + (float)NELEM * b2[0];
}

extern "C" void kernel_launch(void* const* d_in, const int* in_sizes, int n_in,
                              void* d_out, int out_size, void* d_ws, size_t ws_size,
                              hipStream_t stream) {
    (void)in_sizes; (void)n_in; (void)out_size; (void)ws_size;
    const float* pos     = (const float*)d_in[0];
    const float* emb     = (const float*)d_in[1];
    const float* mlp_w1  = (const float*)d_in[2];
    const float* mlp_b1  = (const float*)d_in[3];
    const float* mlp_w2  = (const float*)d_in[4];
    const float* mlp_b2  = (const float*)d_in[5];
    const float* cf1     = (const float*)d_in[6];
    const float* cf2w    = (const float*)d_in[7];
    const float* cf2b    = (const float*)d_in[8];
    const float* intw    = (const float*)d_in[9];
    const float* intb    = (const float*)d_in[10];
    const float* ow1     = (const float*)d_in[11];
    const float* ob1     = (const float*)d_in[12];
    const float* ow2     = (const float*)d_in[13];
    const float* ob2     = (const float*)d_in[14];
    const int*   z       = (const int*)d_in[15];
    const int*   comp_id = (const int*)d_in[16];
    const int*   ei      = (const int*)d_in[17];
    const int*   comps_z = (const int*)d_in[18];
    float* out = (float*)d_out;

    char* ws = (char*)d_ws;
    size_t off = 0;
    auto alloc = [&](size_t bytes) -> void* {
        void* p = ws + off;
        off += (bytes + 255) & ~(size_t)255;
        return p;
    };
    // zeroed prefix: comp_acc | counts | types_acc | cursor | c_s | zsrc_s
    float* comp_acc  = (float*)alloc((size_t)LL * NC * FD * 4);
    int*   counts    = (int*)  alloc(NC * 4);
    float* types_acc = (float*)alloc((size_t)NC * HD * 4);
    int*   cursor    = (int*)  alloc(NC * CSTR * 4);
    float* c_s       = (float*)alloc((size_t)PADE * 4);
    int*   zsrc_s    = (int*)  alloc((size_t)PADE * 4);
    size_t zero_bytes = off;
    float* ew_s     = (float*)alloc((size_t)PADE * 4);
    float* xh_z     = (float*)alloc((size_t)LL * NZ * FD * 4);
    float* b2p      = (float*)alloc((size_t)LL * FD * 4);
    _Float16* w1f   = (_Float16*)alloc((size_t)W1F_ELEMS * 2);
    _Float16* w2f   = (_Float16*)alloc((size_t)W2F_ELEMS * 2);

    hipMemsetAsync(d_ws, 0, zero_bytes, stream);

    setup_kernel<<<NSCATB + NFRAGB + NXHZB + NB2PB, 256, 0, stream>>>(
        pos, ei, comp_id, z, mlp_w1, mlp_w2, mlp_b2, emb, cf1,
        counts, cursor, ew_s, c_s, zsrc_s, w1f, w2f, xh_z, b2p);
    edge_kernel <<<dim3(PADG, LL), 256, 0, stream>>>(ew_s, c_s, zsrc_s,
                                                     w1f, mlp_b1, w2f, b2p,
                                                     xh_z, comp_acc);
    comp_kernel <<<dim3(NC, LL), 128, 0, stream>>>(comp_acc, counts, cf2w, cf2b,
                                                   intw, intb, types_acc);
    readout_kernel<<<NGRAPH, 64, 0, stream>>>(types_acc, emb, comps_z,
                                              ow1, ob1, ow2, ob2, out);
}